// Round 5
// baseline (381.946 us; speedup 1.0000x reference)
//
#include <hip/hip_runtime.h>
#include <hip/hip_bf16.h>
#include <cstdint>

// Problem dims (fixed by reference setup_inputs)
constexpr int Bc  = 2;
constexpr int Lc  = 4096;
constexpr int Hc  = 2048;
constexpr int LKc = 128;
constexpr float LAMc = 0.003f;

typedef __attribute__((ext_vector_type(8)))  __bf16 bf16x8;
typedef __attribute__((ext_vector_type(4)))  float  f32x4;
typedef __attribute__((ext_vector_type(16))) float  f32x16;
typedef __attribute__((ext_vector_type(8)))  unsigned short ushort8;

__device__ __forceinline__ unsigned short f2bf_bits(float v) {
  union { __hip_bfloat16 b; unsigned short u; } cv;
  cv.b = __float2bfloat16(v);
  return cv.u;
}
__device__ __forceinline__ float bf_bits2f(unsigned short u) {
  union { unsigned int i; float f; } cv;
  cv.i = ((unsigned int)u) << 16;
  return cv.f;
}

// ---------------------------------------------------------------------------
// async global->LDS, 16B per lane (GEMM staging)
// ---------------------------------------------------------------------------
__device__ __forceinline__ void gl_lds16(const void* g, void* lds) {
  __builtin_amdgcn_global_load_lds(
      (const __attribute__((address_space(1))) uint32_t*)(uintptr_t)g,
      (__attribute__((address_space(3))) uint32_t*)(uint32_t)(uintptr_t)lds,
      16, 0, 0);
}

// ---------------------------------------------------------------------------
// Kernel 1: tap squash + Hankel MFMA A-fragment precompute. (FROZEN)
// ---------------------------------------------------------------------------
__global__ __launch_bounds__(256) void tapfrag_kernel(
    const float* __restrict__ kin, unsigned short* __restrict__ Afr) {
  const int idx  = blockIdx.x * 256 + threadIdx.x;  // [0, 2048*5*64)
  const int lane = idx & 63;
  const int idx2 = idx >> 6;          // h*5 + cc
  const int h  = idx2 / 5;
  const int cc = idx2 - h * 5;
  const int m = lane & 15, quad = lane >> 4;
  const int jb = m + 32 * cc - 32 + 8 * quad;
  ushort8 o;
#pragma unroll
  for (int jj = 0; jj < 8; ++jj) {
    const int j = jb + jj;
    float v = 0.f;
    if (j >= 0 && j < LKc) {
      const float x = kin[h * LKc + j];
      const float a = fabsf(x) - LAMc;
      v = (a > 0.f) ? copysignf(a, x) : 0.f;
    }
    o[jj] = f2bf_bits(v);
  }
  ((ushort8*)Afr)[idx] = o;
}

// ---------------------------------------------------------------------------
// Kernel 2: W fp32 [2H, H] -> bf16 same layout (FROZEN)
// ---------------------------------------------------------------------------
__global__ __launch_bounds__(256) void wcast_kernel(
    const float* __restrict__ W, __hip_bfloat16* __restrict__ Wb) {
  const int idx = (blockIdx.x * 256 + threadIdx.x) * 4;
  const float4 v = *(const float4*)(W + idx);
  Wb[idx + 0] = __float2bfloat16(v.x);
  Wb[idx + 1] = __float2bfloat16(v.y);
  Wb[idx + 2] = __float2bfloat16(v.z);
  Wb[idx + 3] = __float2bfloat16(v.w);
}

// ---------------------------------------------------------------------------
// Kernel 3: MFMA FIR, 16 h x 512 l per block. (FROZEN this round)
// ---------------------------------------------------------------------------
__global__ __launch_bounds__(256) void conv_mfma_kernel(
    const float* __restrict__ u, const unsigned short* __restrict__ Afr,
    const float* __restrict__ Dp, unsigned short* __restrict__ Am) {
  __shared__ __align__(16) unsigned short ur[16 * 664];  // 21248 B
  __shared__ __align__(16) unsigned short ot[512 * 17];  // 17408 B

  const int t    = threadIdx.x;
  const int lane = t & 63;
  const int wv   = t >> 6;
  const int l16  = lane & 15;
  const int quad = lane >> 4;
  const int l0 = blockIdx.x * 512;
  const int h0 = blockIdx.y * 16;
  const int b  = blockIdx.z;

  const size_t ubase = (size_t)b * Lc * Hc + h0;

#pragma unroll 4
  for (int i = 0; i < 41; ++i) {
    const int e  = (i << 8) + t;
    const int hl = e & 15;
    const int x  = e >> 4;
    const int l  = l0 + 528 - x;
    float v = 0.f;
    if (l >= 0) v = u[ubase + (size_t)min(l, Lc - 1) * Hc + hl];
    ur[hl * 664 + x] = f2bf_bits(v);
  }
  __syncthreads();

#pragma unroll 1
  for (int hi = 0; hi < 4; ++hi) {
    const int hl = (wv << 2) | hi;
    const int h  = h0 + hl;
    bf16x8 af[5];
    const unsigned short* afp = Afr + ((size_t)(h * 5) * 64 + lane) * 8;
#pragma unroll
    for (int cc = 0; cc < 5; ++cc) af[cc] = *(const bf16x8*)(afp + cc * 512);
    const float dv = 2.f * Dp[h];  // duplicated skip line in reference
    const unsigned short* urh = &ur[hl * 664];
#pragma unroll
    for (int nt = 0; nt < 2; ++nt) {
      f32x4 acc = f32x4{0.f, 0.f, 0.f, 0.f};
      const int bbase = 496 - 256 * nt - 16 * l16 + 8 * quad;
#pragma unroll
      for (int cc = 0; cc < 5; ++cc) {
        const bf16x8 bf = *(const bf16x8*)(urh + bbase + 32 * cc);
        acc = __builtin_amdgcn_mfma_f32_16x16x32_bf16(af[cc], bf, acc, 0, 0, 0);
      }
#pragma unroll
      for (int r = 0; r < 4; ++r) {
        const int lc = quad * 4 + r + 16 * l16;
        const float uu = bf_bits2f(urh[528 - 256 * nt - lc]);  // u[l0+256nt+lc]
        const float y = fmaf(dv, uu, acc[r]);
        const float g = 0.5f * y * (1.f + erff(y * 0.70710678118654752f));
        ot[(nt * 256 + lc) * 17 + hl] = f2bf_bits(g);
      }
    }
  }
  __syncthreads();

#pragma unroll
  for (int rr = 0; rr < 2; ++rr) {
    const int lc = (rr << 8) + t;
    const unsigned short* row = &ot[lc * 17];
    unsigned int w[8];
#pragma unroll
    for (int p = 0; p < 8; ++p)
      w[p] = (unsigned int)row[2 * p] | ((unsigned int)row[2 * p + 1] << 16);
    unsigned short* dst = Am + ((size_t)(b * Lc + l0 + lc)) * Hc + h0;
    *(uint4*)(dst)     = make_uint4(w[0], w[1], w[2], w[3]);
    *(uint4*)(dst + 8) = make_uint4(w[4], w[5], w[6], w[7]);
  }
}

// ---------------------------------------------------------------------------
// Kernel 4 (v2): GEMM + bias + GLU on 32x32x16 MFMA (16 FLOP/LDS-byte vs 8).
// Block 128m x 64n_out, 4 waves; wave = 64m x 32n for both a and g halves.
// Per K=32: 8 MFMA + 8 ds_read_b128 (was 16 + 10 for the same FLOP).
// A-frag (32x32x16): m = lane&31, k = 8*(lane>>5)+j  (k-permutation-safe)
// C/D: col = lane&31, row = (reg&3) + 8*(reg>>2) + 4*(lane>>5)  [m74/m101]
// ---------------------------------------------------------------------------
__global__ __launch_bounds__(256, 2) void gemm_glu_kernel(
    const __hip_bfloat16* __restrict__ A, const __hip_bfloat16* __restrict__ Wb,
    const float* __restrict__ bias, float* __restrict__ out) {
  __shared__ __align__(16) __hip_bfloat16 As[128 * 32];  // 8 KB
  __shared__ __align__(16) __hip_bfloat16 Bs[128 * 32];  // rows 0..63=a, 64..127=g

  const int t     = threadIdx.x;
  const int lane  = t & 63;
  const int wv    = t >> 6;
  const int l32   = lane & 31;
  const int khalf = lane >> 5;
  const int mhalf = wv & 1;
  const int nhalf = wv >> 1;
  const int m0 = blockIdx.x * 128;
  const int n0 = blockIdx.y * 64;

  f32x16 accA[2], accG[2];
#pragma unroll
  for (int mi = 0; mi < 2; ++mi) {
    accA[mi] = (f32x16)(0.f);
    accG[mi] = (f32x16)(0.f);
  }

  // staging: chunk c = wv*2+i covers 16 rows x 64B; lane (r=lane>>2, g=lane&3)
  const int srow = lane >> 2;
  const int scol = (lane & 3) * 8;  // bf16 elements
  const int cA0 = wv * 2, cA1 = wv * 2 + 1;
  const __hip_bfloat16* gA0 = A + (size_t)(m0 + cA0 * 16 + srow) * Hc + scol;
  const __hip_bfloat16* gA1 = A + (size_t)(m0 + cA1 * 16 + srow) * Hc + scol;
  // Bs chunks 0..3 = a rows n0+c*16.. ; chunks 4..7 = g rows Hc+n0+(c-4)*16..
  const size_t brow0 = (cA0 < 4) ? (size_t)(n0 + cA0 * 16) : (size_t)(Hc + n0 + (cA0 - 4) * 16);
  const size_t brow1 = (cA1 < 4) ? (size_t)(n0 + cA1 * 16) : (size_t)(Hc + n0 + (cA1 - 4) * 16);
  const __hip_bfloat16* gB0 = Wb + (brow0 + srow) * Hc + scol;
  const __hip_bfloat16* gB1 = Wb + (brow1 + srow) * Hc + scol;
  char* ldsA0 = (char*)As + cA0 * 1024;
  char* ldsA1 = (char*)As + cA1 * 1024;
  char* ldsB0 = (char*)Bs + cA0 * 1024;
  char* ldsB1 = (char*)Bs + cA1 * 1024;

  // fragment read pointers
  const bf16x8* arp[2];
#pragma unroll
  for (int mi = 0; mi < 2; ++mi)
    arp[mi] = (const bf16x8*)(As + (mhalf * 64 + mi * 32 + l32) * 32 + khalf * 8);
  const bf16x8* bap = (const bf16x8*)(Bs + (nhalf * 32 + l32) * 32 + khalf * 8);
  const bf16x8* bgp = (const bf16x8*)(Bs + (64 + nhalf * 32 + l32) * 32 + khalf * 8);

  for (int it = 0; it < 64; ++it) {
    const int k0 = it * 32;
    gl_lds16(gA0 + k0, ldsA0);
    gl_lds16(gA1 + k0, ldsA1);
    gl_lds16(gB0 + k0, ldsB0);
    gl_lds16(gB1 + k0, ldsB1);
    __syncthreads();
#pragma unroll
    for (int kk = 0; kk < 2; ++kk) {  // kk*16 within BK=32 (8 bf16 offset)
      const bf16x8 ba = *(const bf16x8*)((const __hip_bfloat16*)bap + kk * 16);
      const bf16x8 bg = *(const bf16x8*)((const __hip_bfloat16*)bgp + kk * 16);
#pragma unroll
      for (int mi = 0; mi < 2; ++mi) {
        const bf16x8 af = *(const bf16x8*)((const __hip_bfloat16*)arp[mi] + kk * 16);
        accA[mi] = __builtin_amdgcn_mfma_f32_32x32x16_bf16(af, ba, accA[mi], 0, 0, 0);
        accG[mi] = __builtin_amdgcn_mfma_f32_32x32x16_bf16(af, bg, accG[mi], 0, 0, 0);
      }
    }
    __syncthreads();
  }

  // epilogue: n fixed per lane; 32 scalar stores (128B/half-wave, coalesced)
  const int n = n0 + nhalf * 32 + l32;
  const float ba_ = bias[n];
  const float bg_ = bias[Hc + n];
#pragma unroll
  for (int mi = 0; mi < 2; ++mi) {
#pragma unroll
    for (int r = 0; r < 16; ++r) {
      const int row = (r & 3) + 8 * (r >> 2) + 4 * khalf;
      const int m = m0 + mhalf * 64 + mi * 32 + row;
      const float a = accA[mi][r] + ba_;
      const float g = accG[mi][r] + bg_;
      out[(size_t)m * Hc + n] = a * (1.f / (1.f + expf(-g)));
    }
  }
}

// ---------------------------------------------------------------------------
extern "C" void kernel_launch(void* const* d_in, const int* in_sizes, int n_in,
                              void* d_out, int out_size, void* d_ws, size_t ws_size,
                              hipStream_t stream) {
  const float* u    = (const float*)d_in[0];  // [B, L, H]
  const float* kin  = (const float*)d_in[1];  // [1, H, LK]
  const float* Dp   = (const float*)d_in[2];  // [1, H]
  const float* W    = (const float*)d_in[3];  // [2H, H]
  const float* bias = (const float*)d_in[4];  // [2H]
  float* out = (float*)d_out;                 // [B, L, H]

  // ws layout:
  //   [0, 10.5MB)  Afr  (tap fragments; dead after conv)
  //   [0, 16MB)    Wb   (bf16 W; written AFTER conv reads Afr -- same stream)
  //   [16MB, 48MB) Am   (bf16 activations)
  char* ws = (char*)d_ws;
  unsigned short* Afr = (unsigned short*)ws;
  __hip_bfloat16* Wb  = (__hip_bfloat16*)ws;
  unsigned short* Am  = (unsigned short*)(ws + (16 << 20));

  tapfrag_kernel<<<(Hc * 5 * 64) / 256, 256, 0, stream>>>(kin, Afr);
  conv_mfma_kernel<<<dim3(Lc / 512, Hc / 16, Bc), 256, 0, stream>>>(u, Afr, Dp, Am);
  wcast_kernel<<<(2 * Hc * Hc) / 1024, 256, 0, stream>>>(W, Wb);
  gemm_glu_kernel<<<dim3((Bc * Lc) / 128, Hc / 64), 256, 0, stream>>>(
      (const __hip_bfloat16*)Am, Wb, bias, out);
}